// Round 1
// baseline (409.935 us; speedup 1.0000x reference)
//
#include <hip/hip_runtime.h>

typedef __bf16 bf16_t;
typedef __bf16 bf16x2 __attribute__((ext_vector_type(2)));
typedef __bf16 bf16x4 __attribute__((ext_vector_type(4)));
typedef __bf16 bf16x8 __attribute__((ext_vector_type(8)));
typedef float  f32x4  __attribute__((ext_vector_type(4)));

#define NPIX 2048
#define NS   64
#define NK   8
#define NSAMP (NPIX*NS)          // 131072
#define NROWS (NSAMP*NK)         // 1048576
#define TROWS 64
#define NTILES (NROWS/TROWS)     // 16384
#define XSTR 104                 // 96 cols + 8 pad (bf16), rows 16B-aligned
#define HSTR 136                 // 128 cols + 8 pad (bf16), rows 16B-aligned

// packed-weight fragment bases (in bf16x8 units) — pack layout UNCHANGED:
// the B-fragment pack of W is element-identical to the A-fragment pack of W^T.
#define PK_W0 0
#define PK_W1 1536
#define PK_W2 3584
#define PK_WA 5632
#define PK_WR 6656
#define PK_TOT 7680

#define WS_AR_BYTES 122880       // float4 per sample after packed weights

// ---------------------------------------------------------------------------
// Pack W (row-major [KD,ND] fp32), bf16:
// elem e = ((t*KS + s)*64 + l)*8 + j  holds  W[s*32 + (l>>4)*8 + j][t*16 + (l&15)]
// Interpreted as A-fragment of W^T: A[m = l&15][k = s*32+(l>>4)*8+j] = W[k][m].
// ---------------------------------------------------------------------------
__global__ void pack_weights(const float* __restrict__ W0, const float* __restrict__ W1,
                             const float* __restrict__ W2, const float* __restrict__ Wa0,
                             const float* __restrict__ Wr0, bf16_t* __restrict__ dst0) {
  int tid = blockIdx.x * blockDim.x + threadIdx.x;
  if (tid >= PK_TOT * 8) return;
  const float* src; bf16_t* dst; int e, KD, ND, KS;
  if (tid < 12288)      { src = W0;  dst = dst0;         e = tid;         KD = 88;  ND = 128; KS = 3; }
  else if (tid < 28672) { src = W1;  dst = dst0 + 12288; e = tid - 12288; KD = 128; ND = 128; KS = 4; }
  else if (tid < 45056) { src = W2;  dst = dst0 + 28672; e = tid - 28672; KD = 128; ND = 128; KS = 4; }
  else if (tid < 53248) { src = Wa0; dst = dst0 + 45056; e = tid - 45056; KD = 128; ND = 64;  KS = 4; }
  else                  { src = Wr0; dst = dst0 + 53248; e = tid - 53248; KD = 128; ND = 64;  KS = 4; }
  int j = e & 7, l = (e >> 3) & 63, f = e >> 9;
  int s = f % KS, t = f / KS;
  int row = s * 32 + (l >> 4) * 8 + j;
  int col = t * 16 + (l & 15);
  float v = (row < KD) ? src[row * ND + col] : 0.f;
  dst[e] = (bf16_t)v;
}

__device__ __forceinline__ float lrelu(float v) { return fmaxf(v, 0.1f * v); }
__device__ __forceinline__ float sigmoidf(float x) { return 1.f / (1.f + __expf(-x)); }

// ---------------------------------------------------------------------------
// T-design main kernel. Block: 512 thr (8 waves). TRANSPOSED MFMA:
// D = A·B with A = W^T fragments (registers), B = activation fragments
// (contiguous b128 from row-major [sample][k] LDS). Wave w owns out-col tile w.
// All weights persistent in 60 VGPRs (round-6 lesson: L2 is not a safe weight
// home under gather thrash).
//
// Round-7 changes (this round):
//  * T14 async-stage split: tile t+1's gather chain (ind -> map_feat/map_xyz)
//    is issued into registers right after B1 of tile t and committed to LDS at
//    the next loop top — hides the ~1-1.5k-cycle dependent gather latency
//    under the ~9k-cycle compute body (only 2 blocks/CU exist to hide it
//    otherwise; occupancy is VGPR-capped at 16 waves/CU).
//  * Bias regs (20 VGPRs) evicted to LDS; bias folded into MFMA acc init
//    (acc = bias, not acc = 0 + add) — compensates prefetch's ~15 regs to
//    stay under the 128-reg / 4-wave-per-SIMD cliff, and deletes 48
//    v_add_f32 per wave-tile of epilogue VALU.
//  * s_setprio(1) around MFMA clusters (T5): 2 co-resident blocks run
//    phase-staggered -> role diversity for the CU scheduler.
// ---------------------------------------------------------------------------
__global__ __launch_bounds__(512, 4)
void nerf_main(const float* __restrict__ map_xyz, const float* __restrict__ map_feat,
               const int* __restrict__ ind, const float* __restrict__ sample_xyz,
               const float* __restrict__ b0g, const float* __restrict__ b1g,
               const float* __restrict__ b2g, const float* __restrict__ ba0g,
               const float* __restrict__ wa1g, const float* __restrict__ ba1g,
               const float* __restrict__ br0g, const float* __restrict__ wr1g,
               const float* __restrict__ br1g, const bf16_t* __restrict__ wpack,
               float* __restrict__ ar_out)
{
  __shared__ __align__(16) bf16_t sBuf[TROWS * HSTR];   // X (XSTR view) / H2
  __shared__ __align__(16) bf16_t sHa[TROWS * HSTR];    // H1 / H3
  __shared__ __align__(16) bf16_t sFS[16 * HSTR];       // feat_s (rows 8..15 zero)
  __shared__ __align__(16) bf16_t sAR[16 * HSTR];       // [r 0..63 | a 64..127] (rows 8..15 zero)
  __shared__ __align__(16) bf16_t sFB[2048];            // finals A-frags: Wfin^T (128x4, m-padded to 16)
  __shared__ __align__(16) float sWt[TROWS];
  __shared__ float sWs[8];
  // biases live in LDS now (freed 20 persistent VGPRs for the prefetch regs)
  __shared__ __align__(16) float sB0[128], sB1[128], sB2[128], sBH[128], sFBv[4];

  const int tid = threadIdx.x;
  const int wid = tid >> 6, l = tid & 63;
  const int q = l >> 4, n = l & 15;
  const int sr = tid >> 3, sp = tid & 7;   // staging thread coords

  // ---- ALL weights persistent as A-fragments (60 VGPRs) ----
  const bf16x8* pk = (const bf16x8*)wpack;
  bf16x8 w0f[3], w1f[4], w2f[4], hdf[4];
#pragma unroll
  for (int s = 0; s < 3; s++) w0f[s] = pk[PK_W0 + (wid * 3 + s) * 64 + l];
#pragma unroll
  for (int s = 0; s < 4; s++) w1f[s] = pk[PK_W1 + (wid * 4 + s) * 64 + l];
#pragma unroll
  for (int s = 0; s < 4; s++) w2f[s] = pk[PK_W2 + (wid * 4 + s) * 64 + l];
#pragma unroll
  for (int s = 0; s < 4; s++)
    hdf[s] = pk[(wid < 4 ? PK_WA : PK_WR) + ((wid & 3) * 4 + s) * 64 + l];

  // ---- one-time LDS init ----
  for (int i = tid; i < 8 * HSTR; i += 512) {
    sFS[8 * HSTR + i] = (bf16_t)0.f;
    sAR[8 * HSTR + i] = (bf16_t)0.f;
  }
  {  // finals A-frags: A[m][k] = Wfin[k][m]; m<3 -> Wr1 (k<64), m==3 -> Wa1 (k>=64)
    int e0 = tid * 4;
    int jb = e0 & 7, ll = (e0 >> 3) & 63, s = e0 >> 9;
    int m = ll & 15;
#pragma unroll
    for (int ii = 0; ii < 4; ii++) {
      int k = s * 32 + (ll >> 4) * 8 + jb + ii;
      float v = 0.f;
      if (k < 64)  { if (m < 3) v = wr1g[k * 3 + m]; }
      else         { if (m == 3) v = wa1g[k - 64]; }
      sFB[e0 + ii] = (bf16_t)v;
    }
  }
  // biases -> LDS (once)
  if (tid < 128)      sB0[tid] = b0g[tid];
  else if (tid < 256) sB1[tid - 128] = b1g[tid - 128];
  else if (tid < 384) sB2[tid - 256] = b2g[tid - 256];
  else { int t = tid - 384; sBH[t] = (t < 64) ? ba0g[t] : br0g[t - 64]; }
  if (tid < 4) sFBv[tid] = (tid < 3) ? br1g[tid] : ba1g[0];
  __syncthreads();

  // ---- T14 prefetch registers (live across the tile body; ~15 VGPRs) ----
  int   pidx = 0;
  float4 pf0 = {}, pf1 = {};
  float ps0 = 0.f, ps1 = 0.f, ps2 = 0.f, pm0 = 0.f, pm1 = 0.f, pm2 = 0.f;

  auto prefetch = [&](int t) {
    const int m = t * TROWS + sr;
    pidx = ind[m];
    const float4* fp = (const float4*)(map_feat + (size_t)pidx * 64 + sp * 8);
    pf0 = fp[0]; pf1 = fp[1];
    const int g = m >> 3;
    if (sp < 6) {
      const int d = sp >> 1;
      ps0 = sample_xyz[g * 3 + d];
      pm0 = map_xyz[pidx * 3 + d];
    } else if (sp == 7) {
      ps0 = sample_xyz[g * 3 + 0]; pm0 = map_xyz[pidx * 3 + 0];
      ps1 = sample_xyz[g * 3 + 1]; pm1 = map_xyz[pidx * 3 + 1];
      ps2 = sample_xyz[g * 3 + 2]; pm2 = map_xyz[pidx * 3 + 2];
    }
  };

  prefetch(blockIdx.x);   // prologue: first tile's gather (not hidden)

  for (int tile = blockIdx.x; tile < NTILES; tile += gridDim.x) {
    const int m0 = tile * TROWS;

    // ---- commit staged registers -> LDS (X row-major [sample][k]) ----
    {
      bf16x8 v;
      v[0] = (bf16_t)pf0.x; v[1] = (bf16_t)pf0.y; v[2] = (bf16_t)pf0.z; v[3] = (bf16_t)pf0.w;
      v[4] = (bf16_t)pf1.x; v[5] = (bf16_t)pf1.y; v[6] = (bf16_t)pf1.z; v[7] = (bf16_t)pf1.w;
      *(bf16x8*)(sBuf + sr * XSTR + sp * 8) = v;
      if (sp < 6) {
        const int d = sp >> 1;
        float o = ps0 - pm0;
        float s1 = __sinf(o), c1 = __cosf(o);
        float s2 = 2.f * s1 * c1, c2 = 1.f - 2.f * s1 * s1;
        float s4 = 2.f * s2 * c2, c4 = 1.f - 2.f * s2 * s2;
        float s8 = 2.f * s4 * c4, c8 = 1.f - 2.f * s4 * s4;
        bf16x4 e;
        if (sp & 1) { e[0] = (bf16_t)c1; e[1] = (bf16_t)c2; e[2] = (bf16_t)c4; e[3] = (bf16_t)c8; }
        else        { e[0] = (bf16_t)s1; e[1] = (bf16_t)s2; e[2] = (bf16_t)s4; e[3] = (bf16_t)s8; }
        *(bf16x4*)(sBuf + sr * XSTR + 64 + d * 8 + (sp & 1) * 4) = e;
      } else if (sp == 6) {
        bf16x8 z = {};
        *(bf16x8*)(sBuf + sr * XSTR + 88) = z;   // pad cols 88..95 (zero k-rows)
      } else {
        float ox = ps0 - pm0, oy = ps1 - pm1, oz = ps2 - pm2;
        sWt[sr] = __expf(-10.f * sqrtf(ox * ox + oy * oy + oz * oz));
      }
    }
    __syncthreads();   // B1: X, wt ready

    // ---- issue NEXT tile's gather chain now; consumed at next loop top.
    //      Loads are register-only: latency hides under L0..finals compute.
    {
      int nt = tile + (int)gridDim.x;
      if (nt < NTILES) prefetch(nt);
    }

    if (tid < 8) {
      float ss = 0.f;
#pragma unroll
      for (int k = 0; k < 8; k++) ss += sWt[tid * 8 + k];
      sWs[tid] = ss;
    }

    // ---- layer 0 (K=96): B-frags from sBuf(X), D -> sHa ----
    {
      f32x4 b0i = *(const f32x4*)(sB0 + wid * 16 + q * 4);
      f32x4 acc[4] = {b0i, b0i, b0i, b0i};   // bias folded into acc init
      __builtin_amdgcn_s_setprio(1);
#pragma unroll
      for (int st = 0; st < 4; st++)
#pragma unroll
        for (int s = 0; s < 3; s++) {
          bf16x8 b = *(const bf16x8*)(sBuf + (st * 16 + n) * XSTR + s * 32 + q * 8);
          acc[st] = __builtin_amdgcn_mfma_f32_16x16x32_bf16(w0f[s], b, acc[st], 0, 0, 0);
        }
      __builtin_amdgcn_s_setprio(0);
#pragma unroll
      for (int st = 0; st < 4; st++) {
        bf16x4 o;
        o[0] = (bf16_t)lrelu(acc[st][0]);
        o[1] = (bf16_t)lrelu(acc[st][1]);
        o[2] = (bf16_t)lrelu(acc[st][2]);
        o[3] = (bf16_t)lrelu(acc[st][3]);
        *(bf16x4*)(sHa + (st * 16 + n) * HSTR + wid * 16 + q * 4) = o;
      }
    }
    __syncthreads();   // B2: H1 ready

    // ---- layer 1: sHa -> sBuf ----
    {
      f32x4 b1i = *(const f32x4*)(sB1 + wid * 16 + q * 4);
      f32x4 acc[4] = {b1i, b1i, b1i, b1i};
      __builtin_amdgcn_s_setprio(1);
#pragma unroll
      for (int st = 0; st < 4; st++)
#pragma unroll
        for (int s = 0; s < 4; s++) {
          bf16x8 b = *(const bf16x8*)(sHa + (st * 16 + n) * HSTR + s * 32 + q * 8);
          acc[st] = __builtin_amdgcn_mfma_f32_16x16x32_bf16(w1f[s], b, acc[st], 0, 0, 0);
        }
      __builtin_amdgcn_s_setprio(0);
#pragma unroll
      for (int st = 0; st < 4; st++) {
        bf16x4 o;
        o[0] = (bf16_t)lrelu(acc[st][0]);
        o[1] = (bf16_t)lrelu(acc[st][1]);
        o[2] = (bf16_t)lrelu(acc[st][2]);
        o[3] = (bf16_t)lrelu(acc[st][3]);
        *(bf16x4*)(sBuf + (st * 16 + n) * HSTR + wid * 16 + q * 4) = o;
      }
    }
    __syncthreads();   // B3: H2 ready

    // ---- layer 2: sBuf -> sHa (H3) ----
    {
      f32x4 b2i = *(const f32x4*)(sB2 + wid * 16 + q * 4);
      f32x4 acc[4] = {b2i, b2i, b2i, b2i};
      __builtin_amdgcn_s_setprio(1);
#pragma unroll
      for (int st = 0; st < 4; st++)
#pragma unroll
        for (int s = 0; s < 4; s++) {
          bf16x8 b = *(const bf16x8*)(sBuf + (st * 16 + n) * HSTR + s * 32 + q * 8);
          acc[st] = __builtin_amdgcn_mfma_f32_16x16x32_bf16(w2f[s], b, acc[st], 0, 0, 0);
        }
      __builtin_amdgcn_s_setprio(0);
#pragma unroll
      for (int st = 0; st < 4; st++) {
        bf16x4 o;
        o[0] = (bf16_t)lrelu(acc[st][0]);
        o[1] = (bf16_t)lrelu(acc[st][1]);
        o[2] = (bf16_t)lrelu(acc[st][2]);
        o[3] = (bf16_t)lrelu(acc[st][3]);
        *(bf16x4*)(sHa + (st * 16 + n) * HSTR + wid * 16 + q * 4) = o;
      }
    }
    __syncthreads();   // B4: H3 ready

    // ---- K-reduce (round-4 verified scheme): feat_s -> sFS ----
    {
      int g = tid >> 6;
      int c = (tid & 63) * 2;
      float a0 = 0.f, a1 = 0.f;
#pragma unroll
      for (int k = 0; k < 8; k++) {
        float wk = sWt[g * 8 + k];
        unsigned u = *(const unsigned*)(sHa + (g * 8 + k) * HSTR + c);
        a0 += wk * __uint_as_float(u << 16);
        a1 += wk * __uint_as_float(u & 0xffff0000u);
      }
      float inv = 1.f / sWs[g];
      bf16x2 fo;
      fo[0] = (bf16_t)(a0 * inv);
      fo[1] = (bf16_t)(a1 * inv);
      *(bf16x2*)(sFS + g * HSTR + c) = fo;   // single b32 store
    }
    __syncthreads();   // B5: feat_s ready

    // ---- heads (transposed): D[headcol][group]; store bf16x4 -> sAR ----
    {
      f32x4 ha = *(const f32x4*)(sBH + wid * 16 + q * 4);
      __builtin_amdgcn_s_setprio(1);
#pragma unroll
      for (int s = 0; s < 4; s++) {
        bf16x8 b = *(const bf16x8*)(sFS + n * HSTR + s * 32 + q * 8);
        ha = __builtin_amdgcn_mfma_f32_16x16x32_bf16(hdf[s], b, ha, 0, 0, 0);
      }
      __builtin_amdgcn_s_setprio(0);
      if (n < 8) {   // valid sample groups; rows 8..15 of sAR must stay zero
        const int base = (wid < 4) ? 64 : 0;    // a-vals high, r-vals low
        bf16x4 o;
        o[0] = (bf16_t)lrelu(ha[0]);
        o[1] = (bf16_t)lrelu(ha[1]);
        o[2] = (bf16_t)lrelu(ha[2]);
        o[3] = (bf16_t)lrelu(ha[3]);
        *(bf16x4*)(sAR + n * HSTR + base + (wid & 3) * 16 + q * 4) = o;
      }
    }
    __syncthreads();   // B6: sAR ready

    // ---- finals: wave 0, transposed MFMA; lane q=0 holds sample n's float4 ----
    if (wid == 0) {
      f32x4 c = *(const f32x4*)sFBv;
#pragma unroll
      for (int s = 0; s < 4; s++) {
        bf16x8 a = *(const bf16x8*)(sFB + (s * 64 + l) * 8);
        bf16x8 b = *(const bf16x8*)(sAR + n * HSTR + s * 32 + q * 8);
        c = __builtin_amdgcn_mfma_f32_16x16x32_bf16(a, b, c, 0, 0, 0);
      }
      if (q == 0 && n < 8) {   // rows q*4+i = channels 0..3, col n = sample
        float4 o;
        o.x = sigmoidf(c[0]);
        o.y = sigmoidf(c[1]);
        o.z = sigmoidf(c[2]);
        o.w = sigmoidf(c[3]);
        ((float4*)ar_out)[m0 / 8 + n] = o;
      }
    }
    // no trailing barrier: commit writes sBuf/sWt (re-read only after next B1);
    // sAR/sFS rewritten only after next B4/B5, which all threads (incl. the
    // finals wave) reach only after finishing this tile. Prefetch touches only
    // global memory + registers.
  }
}

// ---------------------------------------------------------------------------
// Volume rendering: one wave per ray; lane s holds sample s. All cross-lane
// ops execute with FULL exec mask (round-2/3 lesson: masked-source bpermute).
// ---------------------------------------------------------------------------
__global__ __launch_bounds__(512)
void render_kernel(const float* __restrict__ ar, const float* __restrict__ dcam,
                   float* __restrict__ out) {
  int ray = blockIdx.x * 8 + (threadIdx.x >> 6);
  int s = threadIdx.x & 63;
  float4 v = ((const float4*)ar)[ray * 64 + s];
  float alpha = v.w;
  float t = 1.f - alpha + 1e-10f;
  float p = t;
#pragma unroll
  for (int d = 1; d < 64; d <<= 1) {
    float o = __shfl_up(p, d);
    if (s >= d) p *= o;
  }
  float pm1 = __shfl_up(p, 1);                // unconditional
  float T = (s == 0) ? 1.f : pm1;             // exclusive product
  float bl = alpha * T;
  float dist = 1.f + 1.25f * dcam[ray * 64 + s];
  float cr = v.x * bl, cg = v.y * bl, cb = v.z * bl, cd = dist * bl, ca = bl;
#pragma unroll
  for (int d = 32; d > 0; d >>= 1) {
    cr += __shfl_xor(cr, d);
    cg += __shfl_xor(cg, d);
    cb += __shfl_xor(cb, d);
    cd += __shfl_xor(cd, d);
    ca += __shfl_xor(ca, d);
  }
  if (s == 0) {
    out[ray * 5 + 0] = cr; out[ray * 5 + 1] = cg; out[ray * 5 + 2] = cb;
    out[ray * 5 + 3] = cd; out[ray * 5 + 4] = ca;
  }
}

// ---------------------------------------------------------------------------
extern "C" void kernel_launch(void* const* d_in, const int* in_sizes, int n_in,
                              void* d_out, int out_size, void* d_ws, size_t ws_size,
                              hipStream_t stream) {
  const float* map_xyz    = (const float*)d_in[0];
  const float* map_feat   = (const float*)d_in[1];
  const int*   ind        = (const int*)d_in[2];
  const float* sample_xyz = (const float*)d_in[3];
  const float* dist_cam   = (const float*)d_in[4];
  const float* W0  = (const float*)d_in[5];
  const float* b0  = (const float*)d_in[6];
  const float* W1  = (const float*)d_in[7];
  const float* b1  = (const float*)d_in[8];
  const float* W2  = (const float*)d_in[9];
  const float* b2  = (const float*)d_in[10];
  const float* Wa0 = (const float*)d_in[11];
  const float* ba0 = (const float*)d_in[12];
  const float* Wa1 = (const float*)d_in[13];
  const float* ba1 = (const float*)d_in[14];
  const float* Wr0 = (const float*)d_in[15];
  const float* br0 = (const float*)d_in[16];
  const float* Wr1 = (const float*)d_in[17];
  const float* br1 = (const float*)d_in[18];

  bf16_t* wpack = (bf16_t*)d_ws;
  float*  ar    = (float*)((char*)d_ws + WS_AR_BYTES);

  pack_weights<<<240, 256, 0, stream>>>(W0, W1, W2, Wa0, Wr0, wpack);
  nerf_main<<<512, 512, 0, stream>>>(map_xyz, map_feat, ind, sample_xyz,
                                     b0, b1, b2, ba0, Wa1, ba1, br0, Wr1, br1,
                                     wpack, ar);
  render_kernel<<<256, 512, 0, stream>>>(ar, dist_cam, (float*)d_out);
}

// Round 3
// 396.457 us; speedup vs baseline: 1.0340x; 1.0340x over previous
//
#include <hip/hip_runtime.h>

typedef __bf16 bf16_t;
typedef __bf16 bf16x2 __attribute__((ext_vector_type(2)));
typedef __bf16 bf16x4 __attribute__((ext_vector_type(4)));
typedef __bf16 bf16x8 __attribute__((ext_vector_type(8)));
typedef float  f32x4  __attribute__((ext_vector_type(4)));

#define NPIX 2048
#define NS   64
#define NK   8
#define NSAMP (NPIX*NS)          // 131072
#define NROWS (NSAMP*NK)         // 1048576
#define TROWS 64
#define NTILES (NROWS/TROWS)     // 16384
#define XSTR 104                 // 96 cols + 8 pad (bf16), rows 16B-aligned
#define HSTR 136                 // 128 cols + 8 pad (bf16), rows 16B-aligned

// packed-weight fragment bases (in bf16x8 units) — pack layout UNCHANGED:
// the B-fragment pack of W is element-identical to the A-fragment pack of W^T.
#define PK_W0 0
#define PK_W1 1536
#define PK_W2 3584
#define PK_WA 5632
#define PK_WR 6656
#define PK_TOT 7680

#define WS_AR_BYTES 122880       // float4 per sample after packed weights

// async global->LDS, 16B/lane ONLY (the HW-verified width; round-2 lesson:
// the 12B variant corrupted LDS — lane stride appears to be 16B for x3).
#define GLDS16(g, s) __builtin_amdgcn_global_load_lds(                          \
    (const __attribute__((address_space(1))) void*)(g),                         \
    (__attribute__((address_space(3))) void*)(s), 16, 0, 0)

// ---------------------------------------------------------------------------
// Pack W (row-major [KD,ND] fp32), bf16:
// elem e = ((t*KS + s)*64 + l)*8 + j  holds  W[s*32 + (l>>4)*8 + j][t*16 + (l&15)]
// Interpreted as A-fragment of W^T: A[m = l&15][k = s*32+(l>>4)*8+j] = W[k][m].
// ---------------------------------------------------------------------------
__global__ void pack_weights(const float* __restrict__ W0, const float* __restrict__ W1,
                             const float* __restrict__ W2, const float* __restrict__ Wa0,
                             const float* __restrict__ Wr0, bf16_t* __restrict__ dst0) {
  int tid = blockIdx.x * blockDim.x + threadIdx.x;
  if (tid >= PK_TOT * 8) return;
  const float* src; bf16_t* dst; int e, KD, ND, KS;
  if (tid < 12288)      { src = W0;  dst = dst0;         e = tid;         KD = 88;  ND = 128; KS = 3; }
  else if (tid < 28672) { src = W1;  dst = dst0 + 12288; e = tid - 12288; KD = 128; ND = 128; KS = 4; }
  else if (tid < 45056) { src = W2;  dst = dst0 + 28672; e = tid - 28672; KD = 128; ND = 128; KS = 4; }
  else if (tid < 53248) { src = Wa0; dst = dst0 + 45056; e = tid - 45056; KD = 128; ND = 64;  KS = 4; }
  else                  { src = Wr0; dst = dst0 + 53248; e = tid - 53248; KD = 128; ND = 64;  KS = 4; }
  int j = e & 7, l = (e >> 3) & 63, f = e >> 9;
  int s = f % KS, t = f / KS;
  int row = s * 32 + (l >> 4) * 8 + j;
  int col = t * 16 + (l & 15);
  float v = (row < KD) ? src[row * ND + col] : 0.f;
  dst[e] = (bf16_t)v;
}

__device__ __forceinline__ float lrelu(float v) { return fmaxf(v, 0.1f * v); }
__device__ __forceinline__ float sigmoidf(float x) { return 1.f / (1.f + __expf(-x)); }

// ---------------------------------------------------------------------------
// T-design main kernel. Block: 512 thr (8 waves). TRANSPOSED MFMA:
// D = A·B with A = W^T fragments (registers), B = activation fragments
// (contiguous b128 from row-major [sample][k] LDS). Wave w owns out-col tile w.
// All weights persistent in 60 VGPRs.
//
// Round-9 (this round): gather prefetch via global_load_lds, 16B width only.
//  * sFeat[64][64] f32: next tile's map_feat gather, 2 glds16/wave issued
//    right after B1 (addresses resolved at loop-top), drained at B2's implicit
//    vmcnt(0) under L0 compute. Source-chunk XOR swizzle (chunk ^= row&7):
//    LDS stays linear (glds requirement), commit b128 reads bank-spread.
//  * sVxyz[64*4]: map_xyz gather via GLDS16 (x,y,z + 1 junk float; stride-4
//    rows). Round-2's GLDS12 corrupted LDS (12B lane stride is not 12).
//  * sSxyz (24 floats) via reg+ds_write (wave 1).
//  * commit phase is pure LDS+VALU: no global latency between loop-top and B1.
//    Biases in LDS, folded into MFMA acc-init; setprio around MFMA clusters.
// ---------------------------------------------------------------------------
__global__ __launch_bounds__(512, 4)
void nerf_main(const float* __restrict__ map_xyz, const float* __restrict__ map_feat,
               const int* __restrict__ ind, const float* __restrict__ sample_xyz,
               const float* __restrict__ b0g, const float* __restrict__ b1g,
               const float* __restrict__ b2g, const float* __restrict__ ba0g,
               const float* __restrict__ wa1g, const float* __restrict__ ba1g,
               const float* __restrict__ br0g, const float* __restrict__ wr1g,
               const float* __restrict__ br1g, const bf16_t* __restrict__ wpack,
               float* __restrict__ ar_out)
{
  __shared__ __align__(16) bf16_t sBuf[TROWS * HSTR];   // X (XSTR view) / H2
  __shared__ __align__(16) bf16_t sHa[TROWS * HSTR];    // H1 / H3
  __shared__ __align__(16) bf16_t sFS[16 * HSTR];       // feat_s (rows 8..15 zero)
  __shared__ __align__(16) bf16_t sAR[16 * HSTR];       // [r 0..63 | a 64..127] (rows 8..15 zero)
  __shared__ __align__(16) bf16_t sFB[2048];            // finals A-frags
  __shared__ __align__(16) float sWt[TROWS];
  __shared__ float sWs[8];
  __shared__ __align__(16) float sB0[128], sB1[128], sB2[128], sBH[128], sFBv[4];
  // prefetch landing zones (single-buffered: writes for t+1 start after B1 of t,
  // reads for t happen at loop-top before B1 — disjoint by barrier)
  __shared__ __align__(16) float sFeat[64 * 64];        // 16384 B, chunk-swizzled
  __shared__ __align__(16) float sVxyz[64 * 4];         // x,y,z,junk per row (16B glds)
  __shared__ __align__(16) float sSxyz[32];             // sample_xyz, 8 groups x 3

  const int tid = threadIdx.x;
  const int wid = tid >> 6, l = tid & 63;
  const int q = l >> 4, n = l & 15;
  const int sr = tid >> 3, sp = tid & 7;   // staging thread coords

  // ---- ALL weights persistent as A-fragments (60 VGPRs) ----
  const bf16x8* pk = (const bf16x8*)wpack;
  bf16x8 w0f[3], w1f[4], w2f[4], hdf[4];
#pragma unroll
  for (int s = 0; s < 3; s++) w0f[s] = pk[PK_W0 + (wid * 3 + s) * 64 + l];
#pragma unroll
  for (int s = 0; s < 4; s++) w1f[s] = pk[PK_W1 + (wid * 4 + s) * 64 + l];
#pragma unroll
  for (int s = 0; s < 4; s++) w2f[s] = pk[PK_W2 + (wid * 4 + s) * 64 + l];
#pragma unroll
  for (int s = 0; s < 4; s++)
    hdf[s] = pk[(wid < 4 ? PK_WA : PK_WR) + ((wid & 3) * 4 + s) * 64 + l];

  // ---- prefetch helpers (transient regs only; dead by B2) ----
  int pidxA = 0, pidxB = 0, pidxC = 0;
  float sampv = 0.f;
  auto issueA = [&](int nt) {            // loop-top: resolve addresses (L2-hot)
    const int m0n = nt * TROWS;
    pidxA = ind[m0n + wid * 8 + (l >> 4)];
    pidxB = ind[m0n + wid * 8 + 4 + (l >> 4)];
    if (wid == 0) pidxC = ind[m0n + l];
    if (wid == 1 && l < 24) sampv = sample_xyz[nt * 24 + l];
  };
  auto issueB = [&]() {                  // post-B1: fire async gathers
    // dest slot k = l&15 of row r holds global chunk k ^ (r&7)  (bank spread)
    const int ca = (l & 15) ^ (l >> 4);          // rows wid*8 + 0..3
    const int cb = (l & 15) ^ (4 | (l >> 4));    // rows wid*8 + 4..7
    GLDS16(map_feat + (size_t)pidxA * 64 + ca * 4, sFeat + wid * 512);
    GLDS16(map_feat + (size_t)pidxB * 64 + cb * 4, sFeat + wid * 512 + 256);
    // xyz: 16B/lane (x,y,z,junk) -> stride-4 rows. 4B over-read of the last
    // voxel is safe: map_xyz is d_in[0], not the end of the arena.
    if (wid == 0) GLDS16(map_xyz + (size_t)pidxC * 3, sVxyz);
    if (wid == 1 && l < 24) sSxyz[l] = sampv;
  };

  // ---- one-time LDS init ----
  for (int i = tid; i < 8 * HSTR; i += 512) {
    sFS[8 * HSTR + i] = (bf16_t)0.f;
    sAR[8 * HSTR + i] = (bf16_t)0.f;
  }
  {  // finals A-frags: A[m][k] = Wfin[k][m]; m<3 -> Wr1 (k<64), m==3 -> Wa1 (k>=64)
    int e0 = tid * 4;
    int jb = e0 & 7, ll = (e0 >> 3) & 63, s = e0 >> 9;
    int m = ll & 15;
#pragma unroll
    for (int ii = 0; ii < 4; ii++) {
      int k = s * 32 + (ll >> 4) * 8 + jb + ii;
      float v = 0.f;
      if (k < 64)  { if (m < 3) v = wr1g[k * 3 + m]; }
      else         { if (m == 3) v = wa1g[k - 64]; }
      sFB[e0 + ii] = (bf16_t)v;
    }
  }
  // biases -> LDS (once)
  if (tid < 128)      sB0[tid] = b0g[tid];
  else if (tid < 256) sB1[tid - 128] = b1g[tid - 128];
  else if (tid < 384) sB2[tid - 256] = b2g[tid - 256];
  else { int t = tid - 384; sBH[t] = (t < 64) ? ba0g[t] : br0g[t - 64]; }
  if (tid < 4) sFBv[tid] = (tid < 3) ? br1g[tid] : ba1g[0];

  // prologue prefetch for first tile; init barrier's implicit vmcnt(0) drain
  // guarantees completion + visibility before the first commit.
  issueA(blockIdx.x);
  issueB();
  __syncthreads();

  for (int tile = blockIdx.x; tile < NTILES; tile += gridDim.x) {
    const int m0 = tile * TROWS;
    const int nt = tile + (int)gridDim.x;

    if (nt < NTILES) issueA(nt);   // ind loads; drained (cheap) at B1

    // ---- commit staged LDS (f32) -> sBuf (bf16 X, row-major [sample][k]) ----
    {
      const int sw = sr & 7;
      const float* fb = sFeat + sr * 64;
      f32x4 lo = *(const f32x4*)(fb + (((2 * sp)     ^ sw) << 2));
      f32x4 hi = *(const f32x4*)(fb + (((2 * sp + 1) ^ sw) << 2));
      bf16x8 v;
      v[0] = (bf16_t)lo[0]; v[1] = (bf16_t)lo[1]; v[2] = (bf16_t)lo[2]; v[3] = (bf16_t)lo[3];
      v[4] = (bf16_t)hi[0]; v[5] = (bf16_t)hi[1]; v[6] = (bf16_t)hi[2]; v[7] = (bf16_t)hi[3];
      *(bf16x8*)(sBuf + sr * XSTR + sp * 8) = v;
      if (sp < 6) {
        const int d = sp >> 1;
        float o = sSxyz[(sr >> 3) * 3 + d] - sVxyz[sr * 4 + d];
        float s1 = __sinf(o), c1 = __cosf(o);
        float s2 = 2.f * s1 * c1, c2 = 1.f - 2.f * s1 * s1;
        float s4 = 2.f * s2 * c2, c4 = 1.f - 2.f * s2 * s2;
        float s8 = 2.f * s4 * c4, c8 = 1.f - 2.f * s4 * s4;
        bf16x4 e;
        if (sp & 1) { e[0] = (bf16_t)c1; e[1] = (bf16_t)c2; e[2] = (bf16_t)c4; e[3] = (bf16_t)c8; }
        else        { e[0] = (bf16_t)s1; e[1] = (bf16_t)s2; e[2] = (bf16_t)s4; e[3] = (bf16_t)s8; }
        *(bf16x4*)(sBuf + sr * XSTR + 64 + d * 8 + (sp & 1) * 4) = e;
      } else if (sp == 6) {
        bf16x8 z = {};
        *(bf16x8*)(sBuf + sr * XSTR + 88) = z;   // pad cols 88..95 (zero k-rows)
      } else {
        float ox = sSxyz[(sr >> 3) * 3 + 0] - sVxyz[sr * 4 + 0];
        float oy = sSxyz[(sr >> 3) * 3 + 1] - sVxyz[sr * 4 + 1];
        float oz = sSxyz[(sr >> 3) * 3 + 2] - sVxyz[sr * 4 + 2];
        sWt[sr] = __expf(-10.f * sqrtf(ox * ox + oy * oy + oz * oz));
      }
    }
    __syncthreads();   // B1: X, wt ready (drains loop-top ind loads)

    if (nt < NTILES) issueB();   // async gathers; drained at B2 under L0

    if (tid < 8) {
      float ss = 0.f;
#pragma unroll
      for (int k = 0; k < 8; k++) ss += sWt[tid * 8 + k];
      sWs[tid] = ss;
    }

    // ---- layer 0 (K=96): B-frags from sBuf(X), D -> sHa ----
    {
      f32x4 b0i = *(const f32x4*)(sB0 + wid * 16 + q * 4);
      f32x4 acc[4] = {b0i, b0i, b0i, b0i};   // bias folded into acc init
      __builtin_amdgcn_s_setprio(1);
#pragma unroll
      for (int st = 0; st < 4; st++)
#pragma unroll
        for (int s = 0; s < 3; s++) {
          bf16x8 b = *(const bf16x8*)(sBuf + (st * 16 + n) * XSTR + s * 32 + q * 8);
          acc[st] = __builtin_amdgcn_mfma_f32_16x16x32_bf16(w0f[s], b, acc[st], 0, 0, 0);
        }
      __builtin_amdgcn_s_setprio(0);
#pragma unroll
      for (int st = 0; st < 4; st++) {
        bf16x4 o;
        o[0] = (bf16_t)lrelu(acc[st][0]);
        o[1] = (bf16_t)lrelu(acc[st][1]);
        o[2] = (bf16_t)lrelu(acc[st][2]);
        o[3] = (bf16_t)lrelu(acc[st][3]);
        *(bf16x4*)(sHa + (st * 16 + n) * HSTR + wid * 16 + q * 4) = o;
      }
    }
    __syncthreads();   // B2: H1 ready (drains gather glds under L0 cover)

    // ---- layer 1: sHa -> sBuf ----
    {
      f32x4 b1i = *(const f32x4*)(sB1 + wid * 16 + q * 4);
      f32x4 acc[4] = {b1i, b1i, b1i, b1i};
      __builtin_amdgcn_s_setprio(1);
#pragma unroll
      for (int st = 0; st < 4; st++)
#pragma unroll
        for (int s = 0; s < 4; s++) {
          bf16x8 b = *(const bf16x8*)(sHa + (st * 16 + n) * HSTR + s * 32 + q * 8);
          acc[st] = __builtin_amdgcn_mfma_f32_16x16x32_bf16(w1f[s], b, acc[st], 0, 0, 0);
        }
      __builtin_amdgcn_s_setprio(0);
#pragma unroll
      for (int st = 0; st < 4; st++) {
        bf16x4 o;
        o[0] = (bf16_t)lrelu(acc[st][0]);
        o[1] = (bf16_t)lrelu(acc[st][1]);
        o[2] = (bf16_t)lrelu(acc[st][2]);
        o[3] = (bf16_t)lrelu(acc[st][3]);
        *(bf16x4*)(sBuf + (st * 16 + n) * HSTR + wid * 16 + q * 4) = o;
      }
    }
    __syncthreads();   // B3: H2 ready

    // ---- layer 2: sBuf -> sHa (H3) ----
    {
      f32x4 b2i = *(const f32x4*)(sB2 + wid * 16 + q * 4);
      f32x4 acc[4] = {b2i, b2i, b2i, b2i};
      __builtin_amdgcn_s_setprio(1);
#pragma unroll
      for (int st = 0; st < 4; st++)
#pragma unroll
        for (int s = 0; s < 4; s++) {
          bf16x8 b = *(const bf16x8*)(sBuf + (st * 16 + n) * HSTR + s * 32 + q * 8);
          acc[st] = __builtin_amdgcn_mfma_f32_16x16x32_bf16(w2f[s], b, acc[st], 0, 0, 0);
        }
      __builtin_amdgcn_s_setprio(0);
#pragma unroll
      for (int st = 0; st < 4; st++) {
        bf16x4 o;
        o[0] = (bf16_t)lrelu(acc[st][0]);
        o[1] = (bf16_t)lrelu(acc[st][1]);
        o[2] = (bf16_t)lrelu(acc[st][2]);
        o[3] = (bf16_t)lrelu(acc[st][3]);
        *(bf16x4*)(sHa + (st * 16 + n) * HSTR + wid * 16 + q * 4) = o;
      }
    }
    __syncthreads();   // B4: H3 ready

    // ---- K-reduce (round-4 verified scheme): feat_s -> sFS ----
    {
      int g = tid >> 6;
      int c = (tid & 63) * 2;
      float a0 = 0.f, a1 = 0.f;
#pragma unroll
      for (int k = 0; k < 8; k++) {
        float wk = sWt[g * 8 + k];
        unsigned u = *(const unsigned*)(sHa + (g * 8 + k) * HSTR + c);
        a0 += wk * __uint_as_float(u << 16);
        a1 += wk * __uint_as_float(u & 0xffff0000u);
      }
      float inv = 1.f / sWs[g];
      bf16x2 fo;
      fo[0] = (bf16_t)(a0 * inv);
      fo[1] = (bf16_t)(a1 * inv);
      *(bf16x2*)(sFS + g * HSTR + c) = fo;   // single b32 store
    }
    __syncthreads();   // B5: feat_s ready

    // ---- heads (transposed): D[headcol][group]; store bf16x4 -> sAR ----
    {
      f32x4 ha = *(const f32x4*)(sBH + wid * 16 + q * 4);
      __builtin_amdgcn_s_setprio(1);
#pragma unroll
      for (int s = 0; s < 4; s++) {
        bf16x8 b = *(const bf16x8*)(sFS + n * HSTR + s * 32 + q * 8);
        ha = __builtin_amdgcn_mfma_f32_16x16x32_bf16(hdf[s], b, ha, 0, 0, 0);
      }
      __builtin_amdgcn_s_setprio(0);
      if (n < 8) {   // valid sample groups; rows 8..15 of sAR must stay zero
        const int base = (wid < 4) ? 64 : 0;    // a-vals high, r-vals low
        bf16x4 o;
        o[0] = (bf16_t)lrelu(ha[0]);
        o[1] = (bf16_t)lrelu(ha[1]);
        o[2] = (bf16_t)lrelu(ha[2]);
        o[3] = (bf16_t)lrelu(ha[3]);
        *(bf16x4*)(sAR + n * HSTR + base + (wid & 3) * 16 + q * 4) = o;
      }
    }
    __syncthreads();   // B6: sAR ready (also makes this tile's glds visible
                       //     for next loop-top via B2..B6 drain chain)

    // ---- finals: wave 0, transposed MFMA; lane q=0 holds sample n's float4 ----
    if (wid == 0) {
      f32x4 c = *(const f32x4*)sFBv;
#pragma unroll
      for (int s = 0; s < 4; s++) {
        bf16x8 a = *(const bf16x8*)(sFB + (s * 64 + l) * 8);
        bf16x8 b = *(const bf16x8*)(sAR + n * HSTR + s * 32 + q * 8);
        c = __builtin_amdgcn_mfma_f32_16x16x32_bf16(a, b, c, 0, 0, 0);
      }
      if (q == 0 && n < 8) {   // rows q*4+i = channels 0..3, col n = sample
        float4 o;
        o.x = sigmoidf(c[0]);
        o.y = sigmoidf(c[1]);
        o.z = sigmoidf(c[2]);
        o.w = sigmoidf(c[3]);
        ((float4*)ar_out)[m0 / 8 + n] = o;
      }
    }
    // no trailing barrier: commit writes sBuf/sWt (re-read only after next B1);
    // prefetch landing zones for t+1 were written after B1 of this tile and
    // drained at B2..B6 — visible at next loop-top for all waves.
  }
}

// ---------------------------------------------------------------------------
// Volume rendering: one wave per ray; lane s holds sample s. All cross-lane
// ops execute with FULL exec mask (round-2/3 lesson: masked-source bpermute).
// ---------------------------------------------------------------------------
__global__ __launch_bounds__(512)
void render_kernel(const float* __restrict__ ar, const float* __restrict__ dcam,
                   float* __restrict__ out) {
  int ray = blockIdx.x * 8 + (threadIdx.x >> 6);
  int s = threadIdx.x & 63;
  float4 v = ((const float4*)ar)[ray * 64 + s];
  float alpha = v.w;
  float t = 1.f - alpha + 1e-10f;
  float p = t;
#pragma unroll
  for (int d = 1; d < 64; d <<= 1) {
    float o = __shfl_up(p, d);
    if (s >= d) p *= o;
  }
  float pm1 = __shfl_up(p, 1);                // unconditional
  float T = (s == 0) ? 1.f : pm1;             // exclusive product
  float bl = alpha * T;
  float dist = 1.f + 1.25f * dcam[ray * 64 + s];
  float cr = v.x * bl, cg = v.y * bl, cb = v.z * bl, cd = dist * bl, ca = bl;
#pragma unroll
  for (int d = 32; d > 0; d >>= 1) {
    cr += __shfl_xor(cr, d);
    cg += __shfl_xor(cg, d);
    cb += __shfl_xor(cb, d);
    cd += __shfl_xor(cd, d);
    ca += __shfl_xor(ca, d);
  }
  if (s == 0) {
    out[ray * 5 + 0] = cr; out[ray * 5 + 1] = cg; out[ray * 5 + 2] = cb;
    out[ray * 5 + 3] = cd; out[ray * 5 + 4] = ca;
  }
}

// ---------------------------------------------------------------------------
extern "C" void kernel_launch(void* const* d_in, const int* in_sizes, int n_in,
                              void* d_out, int out_size, void* d_ws, size_t ws_size,
                              hipStream_t stream) {
  const float* map_xyz    = (const float*)d_in[0];
  const float* map_feat   = (const float*)d_in[1];
  const int*   ind        = (const int*)d_in[2];
  const float* sample_xyz = (const float*)d_in[3];
  const float* dist_cam   = (const float*)d_in[4];
  const float* W0  = (const float*)d_in[5];
  const float* b0  = (const float*)d_in[6];
  const float* W1  = (const float*)d_in[7];
  const float* b1  = (const float*)d_in[8];
  const float* W2  = (const float*)d_in[9];
  const float* b2  = (const float*)d_in[10];
  const float* Wa0 = (const float*)d_in[11];
  const float* ba0 = (const float*)d_in[12];
  const float* Wa1 = (const float*)d_in[13];
  const float* ba1 = (const float*)d_in[14];
  const float* Wr0 = (const float*)d_in[15];
  const float* br0 = (const float*)d_in[16];
  const float* Wr1 = (const float*)d_in[17];
  const float* br1 = (const float*)d_in[18];

  bf16_t* wpack = (bf16_t*)d_ws;
  float*  ar    = (float*)((char*)d_ws + WS_AR_BYTES);

  pack_weights<<<240, 256, 0, stream>>>(W0, W1, W2, Wa0, Wr0, wpack);
  nerf_main<<<512, 512, 0, stream>>>(map_xyz, map_feat, ind, sample_xyz,
                                     b0, b1, b2, ba0, Wa1, ba1, br0, Wr1, br1,
                                     wpack, ar);
  render_kernel<<<256, 512, 0, stream>>>(ar, dist_cam, (float*)d_out);
}

// Round 4
// 393.948 us; speedup vs baseline: 1.0406x; 1.0064x over previous
//
#include <hip/hip_runtime.h>

typedef __bf16 bf16_t;
typedef __bf16 bf16x2 __attribute__((ext_vector_type(2)));
typedef __bf16 bf16x4 __attribute__((ext_vector_type(4)));
typedef __bf16 bf16x8 __attribute__((ext_vector_type(8)));
typedef float  f32x4  __attribute__((ext_vector_type(4)));

#define NPIX 2048
#define NS   64
#define NK   8
#define NSAMP (NPIX*NS)          // 131072
#define NROWS (NSAMP*NK)         // 1048576
#define TROWS 64
#define NTILES (NROWS/TROWS)     // 16384
#define GRID   512
#define NIT    16                // 32 tiles/block = 16 A-tiles + 16 B-tiles
#define XSTR 104                 // 96 cols + 8 pad (bf16), rows 16B-aligned
#define HSTR 136                 // 128 cols + 8 pad (bf16), rows 16B-aligned

// packed-weight fragment bases (in bf16x8 units) — pack layout UNCHANGED:
// the B-fragment pack of W is element-identical to the A-fragment pack of W^T.
#define PK_W0 0
#define PK_W1 1536
#define PK_W2 3584
#define PK_WA 5632
#define PK_WR 6656
#define PK_TOT 7680

#define WS_AR_BYTES 122880       // float4 per sample after packed weights

// ---------------------------------------------------------------------------
// Pack W (row-major [KD,ND] fp32), bf16:
// elem e = ((t*KS + s)*64 + l)*8 + j  holds  W[s*32 + (l>>4)*8 + j][t*16 + (l&15)]
// Interpreted as A-fragment of W^T: A[m = l&15][k = s*32+(l>>4)*8+j] = W[k][m].
// ---------------------------------------------------------------------------
__global__ void pack_weights(const float* __restrict__ W0, const float* __restrict__ W1,
                             const float* __restrict__ W2, const float* __restrict__ Wa0,
                             const float* __restrict__ Wr0, bf16_t* __restrict__ dst0) {
  int tid = blockIdx.x * blockDim.x + threadIdx.x;
  if (tid >= PK_TOT * 8) return;
  const float* src; bf16_t* dst; int e, KD, ND, KS;
  if (tid < 12288)      { src = W0;  dst = dst0;         e = tid;         KD = 88;  ND = 128; KS = 3; }
  else if (tid < 28672) { src = W1;  dst = dst0 + 12288; e = tid - 12288; KD = 128; ND = 128; KS = 4; }
  else if (tid < 45056) { src = W2;  dst = dst0 + 28672; e = tid - 28672; KD = 128; ND = 128; KS = 4; }
  else if (tid < 53248) { src = Wa0; dst = dst0 + 45056; e = tid - 45056; KD = 128; ND = 64;  KS = 4; }
  else                  { src = Wr0; dst = dst0 + 53248; e = tid - 53248; KD = 128; ND = 64;  KS = 4; }
  int j = e & 7, l = (e >> 3) & 63, f = e >> 9;
  int s = f % KS, t = f / KS;
  int row = s * 32 + (l >> 4) * 8 + j;
  int col = t * 16 + (l & 15);
  float v = (row < KD) ? src[row * ND + col] : 0.f;
  dst[e] = (bf16_t)v;
}

__device__ __forceinline__ float lrelu(float v) { return fmaxf(v, 0.1f * v); }
__device__ __forceinline__ float sigmoidf(float x) { return 1.f / (1.f + __expf(-x)); }

// ---------------------------------------------------------------------------
// Round-10: DUAL-STREAM SOFTWARE PIPELINE.
// Diagnosis: all-waves-same-phase lockstep left every phase's latency chain
// (ds_read ~120cy, gather ~300cy, serial VALU) uncovered — MfmaUtil 18 /
// VALUBusy 33 / LDS ~60% but wall time 2x the max pipe. Occupancy is VGPR-
// capped at 16 waves/CU, so the fix must come from INTRA-phase role diversity.
// The block's 32 tiles split into stream A (even j) and B (odd j), offset by
// 3 of the 6 phases; each barrier-to-barrier phase = one MFMA-heavy op of one
// stream + one VALU/mem-heavy op of the other (buffer-disjoint -> ILP):
//   p1: commitA | L2B     | finalsA      p4: L2A | commitB | finalsB
//   p2: L0A     | kredB   (+sWsA)       p5: kredA | L0B    (+sWsB)
//   p3: L1A     | headsB                p6: headsA | L1B
// Buffer schedule (static, verified): sX: A[p1,p2] B[p4,p5];
//   H0: A.H1[p2,p3] A.H3[p4,p5] B.H2[p6,p1'];  H1: B.H3[p1,p2] A.H2[p3,p4]
//   B.H1[p5,p6];  sFS: A[p5,p6] B[p2,p3];  sAR: A[p6,p1'] B[p3,p4].
// Gather prefetch dropped (round-3: only -3%); commit's gather latency now
// hides under the co-phase MFMA cluster. Weights persistent in 60 VGPRs;
// biases in LDS folded into acc-init; setprio around MFMA clusters.
// ---------------------------------------------------------------------------
__global__ __launch_bounds__(512, 4)
void nerf_main(const float* __restrict__ map_xyz, const float* __restrict__ map_feat,
               const int* __restrict__ ind, const float* __restrict__ sample_xyz,
               const float* __restrict__ b0g, const float* __restrict__ b1g,
               const float* __restrict__ b2g, const float* __restrict__ ba0g,
               const float* __restrict__ wa1g, const float* __restrict__ ba1g,
               const float* __restrict__ br0g, const float* __restrict__ wr1g,
               const float* __restrict__ br1g, const bf16_t* __restrict__ wpack,
               float* __restrict__ ar_out)
{
  __shared__ __align__(16) bf16_t sH0[TROWS * HSTR];    // rotating H buffer
  __shared__ __align__(16) bf16_t sH1[TROWS * HSTR];    // rotating H buffer
  __shared__ __align__(16) bf16_t sX[TROWS * XSTR];     // X, time-shared A/B
  __shared__ __align__(16) bf16_t sFS[16 * HSTR];       // feat_s (rows 8..15 zero)
  __shared__ __align__(16) bf16_t sAR[16 * HSTR];       // [r|a] (rows 8..15 zero)
  __shared__ __align__(16) bf16_t sFB[2048];            // finals A-frags
  __shared__ __align__(16) float sWtA[TROWS], sWtB[TROWS];
  __shared__ float sWsA[8], sWsB[8];
  __shared__ __align__(16) float sB0[128], sB1[128], sB2[128], sBH[128], sFBv[4];

  const int tid = threadIdx.x;
  const int wid = tid >> 6, l = tid & 63;
  const int q = l >> 4, n = l & 15;
  const int sr = tid >> 3, sp = tid & 7;   // staging thread coords

  // ---- ALL weights persistent as A-fragments (60 VGPRs) ----
  const bf16x8* pk = (const bf16x8*)wpack;
  bf16x8 w0f[3], w1f[4], w2f[4], hdf[4];
#pragma unroll
  for (int s = 0; s < 3; s++) w0f[s] = pk[PK_W0 + (wid * 3 + s) * 64 + l];
#pragma unroll
  for (int s = 0; s < 4; s++) w1f[s] = pk[PK_W1 + (wid * 4 + s) * 64 + l];
#pragma unroll
  for (int s = 0; s < 4; s++) w2f[s] = pk[PK_W2 + (wid * 4 + s) * 64 + l];
#pragma unroll
  for (int s = 0; s < 4; s++)
    hdf[s] = pk[(wid < 4 ? PK_WA : PK_WR) + ((wid & 3) * 4 + s) * 64 + l];

  // ---- phase ops (lambdas; buffer pointers passed per call-site) ----
  auto COMMIT = [&](int tile, bf16_t* X, float* wtbuf) {
    const int m = tile * TROWS + sr;
    const int idx = ind[m];
    const float4* fp = (const float4*)(map_feat + (size_t)idx * 64 + sp * 8);
    float4 f0 = fp[0], f1 = fp[1];
    bf16x8 v;
    v[0] = (bf16_t)f0.x; v[1] = (bf16_t)f0.y; v[2] = (bf16_t)f0.z; v[3] = (bf16_t)f0.w;
    v[4] = (bf16_t)f1.x; v[5] = (bf16_t)f1.y; v[6] = (bf16_t)f1.z; v[7] = (bf16_t)f1.w;
    *(bf16x8*)(X + sr * XSTR + sp * 8) = v;
    const int g = m >> 3;
    if (sp < 6) {
      const int d = sp >> 1;
      float o = sample_xyz[g * 3 + d] - map_xyz[idx * 3 + d];
      float s1 = __sinf(o), c1 = __cosf(o);
      float s2 = 2.f * s1 * c1, c2 = 1.f - 2.f * s1 * s1;
      float s4 = 2.f * s2 * c2, c4 = 1.f - 2.f * s2 * s2;
      float s8 = 2.f * s4 * c4, c8 = 1.f - 2.f * s4 * s4;
      bf16x4 e;
      if (sp & 1) { e[0] = (bf16_t)c1; e[1] = (bf16_t)c2; e[2] = (bf16_t)c4; e[3] = (bf16_t)c8; }
      else        { e[0] = (bf16_t)s1; e[1] = (bf16_t)s2; e[2] = (bf16_t)s4; e[3] = (bf16_t)s8; }
      *(bf16x4*)(X + sr * XSTR + 64 + d * 8 + (sp & 1) * 4) = e;
    } else if (sp == 6) {
      bf16x8 z = {};
      *(bf16x8*)(X + sr * XSTR + 88) = z;   // pad cols 88..95 (zero k-rows)
    } else {
      float ox = sample_xyz[g * 3 + 0] - map_xyz[idx * 3 + 0];
      float oy = sample_xyz[g * 3 + 1] - map_xyz[idx * 3 + 1];
      float oz = sample_xyz[g * 3 + 2] - map_xyz[idx * 3 + 2];
      wtbuf[sr] = __expf(-10.f * sqrtf(ox * ox + oy * oy + oz * oz));
    }
  };

  auto L0 = [&](const bf16_t* X, bf16_t* Hout) {
    f32x4 bi = *(const f32x4*)(sB0 + wid * 16 + q * 4);
    f32x4 acc[4] = {bi, bi, bi, bi};
    __builtin_amdgcn_s_setprio(1);
#pragma unroll
    for (int st = 0; st < 4; st++)
#pragma unroll
      for (int s = 0; s < 3; s++) {
        bf16x8 b = *(const bf16x8*)(X + (st * 16 + n) * XSTR + s * 32 + q * 8);
        acc[st] = __builtin_amdgcn_mfma_f32_16x16x32_bf16(w0f[s], b, acc[st], 0, 0, 0);
      }
    __builtin_amdgcn_s_setprio(0);
#pragma unroll
    for (int st = 0; st < 4; st++) {
      bf16x4 o;
      o[0] = (bf16_t)lrelu(acc[st][0]);
      o[1] = (bf16_t)lrelu(acc[st][1]);
      o[2] = (bf16_t)lrelu(acc[st][2]);
      o[3] = (bf16_t)lrelu(acc[st][3]);
      *(bf16x4*)(Hout + (st * 16 + n) * HSTR + wid * 16 + q * 4) = o;
    }
  };

  auto LAYER = [&](const bf16_t* Hin, bf16_t* Hout, const bf16x8* wf, const float* bg) {
    f32x4 bi = *(const f32x4*)(bg + wid * 16 + q * 4);
    f32x4 acc[4] = {bi, bi, bi, bi};
    __builtin_amdgcn_s_setprio(1);
#pragma unroll
    for (int st = 0; st < 4; st++)
#pragma unroll
      for (int s = 0; s < 4; s++) {
        bf16x8 b = *(const bf16x8*)(Hin + (st * 16 + n) * HSTR + s * 32 + q * 8);
        acc[st] = __builtin_amdgcn_mfma_f32_16x16x32_bf16(wf[s], b, acc[st], 0, 0, 0);
      }
    __builtin_amdgcn_s_setprio(0);
#pragma unroll
    for (int st = 0; st < 4; st++) {
      bf16x4 o;
      o[0] = (bf16_t)lrelu(acc[st][0]);
      o[1] = (bf16_t)lrelu(acc[st][1]);
      o[2] = (bf16_t)lrelu(acc[st][2]);
      o[3] = (bf16_t)lrelu(acc[st][3]);
      *(bf16x4*)(Hout + (st * 16 + n) * HSTR + wid * 16 + q * 4) = o;
    }
  };

  auto KRED = [&](const bf16_t* Hin, const float* wt, const float* ws, bf16_t* FS) {
    int g = tid >> 6;
    int c = (tid & 63) * 2;
    float a0 = 0.f, a1 = 0.f;
#pragma unroll
    for (int k = 0; k < 8; k++) {
      float wk = wt[g * 8 + k];
      unsigned u = *(const unsigned*)(Hin + (g * 8 + k) * HSTR + c);
      a0 += wk * __uint_as_float(u << 16);
      a1 += wk * __uint_as_float(u & 0xffff0000u);
    }
    float inv = 1.f / ws[g];
    bf16x2 fo;
    fo[0] = (bf16_t)(a0 * inv);
    fo[1] = (bf16_t)(a1 * inv);
    *(bf16x2*)(FS + g * HSTR + c) = fo;
  };

  auto HEADS = [&](const bf16_t* FS, bf16_t* AR) {
    f32x4 ha = *(const f32x4*)(sBH + wid * 16 + q * 4);
    __builtin_amdgcn_s_setprio(1);
#pragma unroll
    for (int s = 0; s < 4; s++) {
      bf16x8 b = *(const bf16x8*)(FS + n * HSTR + s * 32 + q * 8);
      ha = __builtin_amdgcn_mfma_f32_16x16x32_bf16(hdf[s], b, ha, 0, 0, 0);
    }
    __builtin_amdgcn_s_setprio(0);
    if (n < 8) {   // valid sample groups; rows 8..15 of sAR stay zero
      const int base = (wid < 4) ? 64 : 0;    // a-vals high, r-vals low
      bf16x4 o;
      o[0] = (bf16_t)lrelu(ha[0]);
      o[1] = (bf16_t)lrelu(ha[1]);
      o[2] = (bf16_t)lrelu(ha[2]);
      o[3] = (bf16_t)lrelu(ha[3]);
      *(bf16x4*)(AR + n * HSTR + base + (wid & 3) * 16 + q * 4) = o;
    }
  };

  auto FINALS = [&](int tile) {
    if (wid == 0) {
      f32x4 c = *(const f32x4*)sFBv;
#pragma unroll
      for (int s = 0; s < 4; s++) {
        bf16x8 a = *(const bf16x8*)(sFB + (s * 64 + l) * 8);
        bf16x8 b = *(const bf16x8*)(sAR + n * HSTR + s * 32 + q * 8);
        c = __builtin_amdgcn_mfma_f32_16x16x32_bf16(a, b, c, 0, 0, 0);
      }
      if (q == 0 && n < 8) {
        float4 o;
        o.x = sigmoidf(c[0]);
        o.y = sigmoidf(c[1]);
        o.z = sigmoidf(c[2]);
        o.w = sigmoidf(c[3]);
        ((float4*)ar_out)[tile * 8 + n] = o;
      }
    }
  };

  // ---- one-time LDS init ----
  for (int i = tid; i < 8 * HSTR; i += 512) {
    sFS[8 * HSTR + i] = (bf16_t)0.f;
    sAR[8 * HSTR + i] = (bf16_t)0.f;
  }
  {  // finals A-frags: A[m][k] = Wfin[k][m]; m<3 -> Wr1 (k<64), m==3 -> Wa1 (k>=64)
    int e0 = tid * 4;
    int jb = e0 & 7, ll = (e0 >> 3) & 63, s = e0 >> 9;
    int m = ll & 15;
#pragma unroll
    for (int ii = 0; ii < 4; ii++) {
      int k = s * 32 + (ll >> 4) * 8 + jb + ii;
      float v = 0.f;
      if (k < 64)  { if (m < 3) v = wr1g[k * 3 + m]; }
      else         { if (m == 3) v = wa1g[k - 64]; }
      sFB[e0 + ii] = (bf16_t)v;
    }
  }
  if (tid < 128)      sB0[tid] = b0g[tid];
  else if (tid < 256) sB1[tid - 128] = b1g[tid - 128];
  else if (tid < 384) sB2[tid - 256] = b2g[tid - 256];
  else { int t = tid - 384; sBH[t] = (t < 64) ? ba0g[t] : br0g[t - 64]; }
  if (tid < 4) sFBv[tid] = (tid < 3) ? br1g[tid] : ba1g[0];
  __syncthreads();

  // ---- pipeline: A tiles j=2it, B tiles j=2it+1 (j = tile index / GRID) ----
  for (int it = 0; it <= NIT; ++it) {
    const bool a_on = (it < NIT);
    const bool b_on = (it > 0);
    const int tA  = (int)blockIdx.x + (2 * it) * GRID;
    const int tAp = (int)blockIdx.x + (2 * it - 2) * GRID;
    const int tB  = (int)blockIdx.x + (2 * it + 1) * GRID;
    const int tBp = (int)blockIdx.x + (2 * it - 1) * GRID;

    // ---- p1: commitA(sX) | L2B(H0->H1) | finalsA ----
    if (a_on) COMMIT(tA, sX, sWtA);
    if (b_on) LAYER(sH0, sH1, w2f, sB2);
    if (b_on) FINALS(tAp);
    __syncthreads();

    // ---- p2: L0A(sX->H0) | kredB(H1) | sWsA ----
    if (a_on) L0(sX, sH0);
    if (b_on) KRED(sH1, sWtB, sWsB, sFS);
    if (a_on && tid < 8) {
      float ss = 0.f;
#pragma unroll
      for (int k = 0; k < 8; k++) ss += sWtA[tid * 8 + k];
      sWsA[tid] = ss;
    }
    __syncthreads();

    // ---- p3: L1A(H0->H1) | headsB(sFS->sAR) ----
    if (a_on) LAYER(sH0, sH1, w1f, sB1);
    if (b_on) HEADS(sFS, sAR);
    __syncthreads();

    // ---- p4: L2A(H1->H0) | commitB(sX) | finalsB ----
    if (a_on) COMMIT(tB, sX, sWtB);
    if (a_on) LAYER(sH1, sH0, w2f, sB2);
    if (b_on) FINALS(tBp);
    __syncthreads();

    if (it == NIT) break;   // drain complete (uniform exit)

    // ---- p5: kredA(H0) | L0B(sX->H1) | sWsB ----
    L0(sX, sH1);
    KRED(sH0, sWtA, sWsA, sFS);
    if (tid < 8) {
      float ss = 0.f;
#pragma unroll
      for (int k = 0; k < 8; k++) ss += sWtB[tid * 8 + k];
      sWsB[tid] = ss;
    }
    __syncthreads();

    // ---- p6: headsA(sFS->sAR) | L1B(H1->H0) ----
    LAYER(sH1, sH0, w1f, sB1);
    HEADS(sFS, sAR);
    __syncthreads();
  }
}

// ---------------------------------------------------------------------------
// Volume rendering: one wave per ray; lane s holds sample s. All cross-lane
// ops execute with FULL exec mask (round-2/3 lesson: masked-source bpermute).
// ---------------------------------------------------------------------------
__global__ __launch_bounds__(512)
void render_kernel(const float* __restrict__ ar, const float* __restrict__ dcam,
                   float* __restrict__ out) {
  int ray = blockIdx.x * 8 + (threadIdx.x >> 6);
  int s = threadIdx.x & 63;
  float4 v = ((const float4*)ar)[ray * 64 + s];
  float alpha = v.w;
  float t = 1.f - alpha + 1e-10f;
  float p = t;
#pragma unroll
  for (int d = 1; d < 64; d <<= 1) {
    float o = __shfl_up(p, d);
    if (s >= d) p *= o;
  }
  float pm1 = __shfl_up(p, 1);                // unconditional
  float T = (s == 0) ? 1.f : pm1;             // exclusive product
  float bl = alpha * T;
  float dist = 1.f + 1.25f * dcam[ray * 64 + s];
  float cr = v.x * bl, cg = v.y * bl, cb = v.z * bl, cd = dist * bl, ca = bl;
#pragma unroll
  for (int d = 32; d > 0; d >>= 1) {
    cr += __shfl_xor(cr, d);
    cg += __shfl_xor(cg, d);
    cb += __shfl_xor(cb, d);
    cd += __shfl_xor(cd, d);
    ca += __shfl_xor(ca, d);
  }
  if (s == 0) {
    out[ray * 5 + 0] = cr; out[ray * 5 + 1] = cg; out[ray * 5 + 2] = cb;
    out[ray * 5 + 3] = cd; out[ray * 5 + 4] = ca;
  }
}

// ---------------------------------------------------------------------------
extern "C" void kernel_launch(void* const* d_in, const int* in_sizes, int n_in,
                              void* d_out, int out_size, void* d_ws, size_t ws_size,
                              hipStream_t stream) {
  const float* map_xyz    = (const float*)d_in[0];
  const float* map_feat   = (const float*)d_in[1];
  const int*   ind        = (const int*)d_in[2];
  const float* sample_xyz = (const float*)d_in[3];
  const float* dist_cam   = (const float*)d_in[4];
  const float* W0  = (const float*)d_in[5];
  const float* b0  = (const float*)d_in[6];
  const float* W1  = (const float*)d_in[7];
  const float* b1  = (const float*)d_in[8];
  const float* W2  = (const float*)d_in[9];
  const float* b2  = (const float*)d_in[10];
  const float* Wa0 = (const float*)d_in[11];
  const float* ba0 = (const float*)d_in[12];
  const float* Wa1 = (const float*)d_in[13];
  const float* ba1 = (const float*)d_in[14];
  const float* Wr0 = (const float*)d_in[15];
  const float* br0 = (const float*)d_in[16];
  const float* Wr1 = (const float*)d_in[17];
  const float* br1 = (const float*)d_in[18];

  bf16_t* wpack = (bf16_t*)d_ws;
  float*  ar    = (float*)((char*)d_ws + WS_AR_BYTES);

  pack_weights<<<240, 256, 0, stream>>>(W0, W1, W2, Wa0, Wr0, wpack);
  nerf_main<<<GRID, 512, 0, stream>>>(map_xyz, map_feat, ind, sample_xyz,
                                      b0, b1, b2, ba0, Wa1, ba1, br0, Wr1, br1,
                                      wpack, ar);
  render_kernel<<<256, 512, 0, stream>>>(ar, dist_cam, (float*)d_out);
}